// Round 10
// baseline (151.324 us; speedup 1.0000x reference)
//
#include <hip/hip_runtime.h>
#include <hip/hip_bf16.h>
#include <math.h>

constexpr int HS = 32;      // half spatial (32x32 grids)
constexpr int Lq = 1024;    // HS*HS
constexpr int CN = 128;     // channels
// batches = 2. Inputs fp32 (f, b, mask). Output fp32 (r11-verified).
// R28: ABLATION round — k_gemm_mfma launched TWICE (pure overwrite of P, idempotent,
// bit-identical output). Marginal dur = true gemm cost. Decision rule:
//   >=12us -> R29 restructures gemm tile (MFMA:ds ratio); <8us -> gemm done, pivot.
// All kernel code byte-identical to r27 (136.35 best measured).
// History: gemm 48.8us (r23 PMC) -> +swizzle+dbuf -> +static dbuf+4blk/CU ->
// +counted-vmcnt (r27, NULL => TLP already hides staging latency at 16 waves/CU).

typedef short bf16x8 __attribute__((ext_vector_type(8)));
typedef float f32x4  __attribute__((ext_vector_type(4)));

__device__ inline unsigned short f2bf(float x) {   // RNE float->bf16 bits
    union { float f; unsigned int u; } c; c.f = x;
    return (unsigned short)((c.u + 0x7FFF + ((c.u >> 16) & 1)) >> 16);
}
__device__ inline float bf2f(unsigned short h) {
    union { unsigned int u; float f; } c; c.u = ((unsigned int)h) << 16;
    return c.f;
}

// async global->LDS, 16B per lane (wave-uniform LDS base + lane*16 layout)
__device__ inline void gload16(const void* g, void* l) {
    __builtin_amdgcn_global_load_lds(
        (const __attribute__((address_space(1))) unsigned int*)g,
        (__attribute__((address_space(3))) unsigned int*)l, 16, 0, 0);
}

// ---------------- merged prep+ssq+wm: one launch, two grid segments ----------------
__global__ __launch_bounds__(256) void k_prep3(const float* __restrict__ f,
                                               const float* __restrict__ bsrc,
                                               unsigned short* __restrict__ fH, unsigned short* __restrict__ fL,
                                               unsigned short* __restrict__ bH, unsigned short* __restrict__ bL,
                                               float* __restrict__ ssq,
                                               unsigned short* __restrict__ Wm) {
    int tx = threadIdx.x;
    if (blockIdx.x < 512) {
        int u = blockIdx.x * 4 + (tx >> 6);  // 0..2047 = bb*1024 + p
        int lane = tx & 63;
        int p = u & (Lq - 1), bb = u >> 10;
        int py = p >> 5, px = p & 31;
        long srcbase = (((long)bb * CN) * 64 + 2 * py) * 64 + 2 * px;
        float s = 0.f;
#pragma unroll
        for (int i = 0; i < 2; ++i) {
            int c = lane + i * 64;
            long src = srcbase + (long)c * 4096;
            float fv = f[src], bv = bsrc[src];
            int o = u * CN + c;
            unsigned short fh = f2bf(fv), bh = f2bf(bv);
            fH[o] = fh; fL[o] = f2bf(fv - bf2f(fh));
            bH[o] = bh; bL[o] = f2bf(bv - bf2f(bh));
            s += bv * bv;
        }
        for (int off = 32; off > 0; off >>= 1) s += __shfl_down(s, off, 64);
        if (lane == 0) ssq[u] = s;
    } else {
        int idx = (blockIdx.x - 512) * 256 + tx;   // 2*2048*1024
        int q  = idx & (Lq - 1);
        int m  = (idx >> 10) & 2047;
        int bb = idx >> 21;
        int c = m >> 4, u = (m >> 2) & 3, v = m & 3;
        int qy = q >> 5, qx = q & 31;
        int y = 2 * qy + u - 1, x = 2 * qx + v - 1;
        float val = 0.f;
        if ((unsigned)y < 64u && (unsigned)x < 64u)
            val = bsrc[(((long)bb * CN + c) * 64 + y) * 64 + x];
        Wm[idx] = f2bf(val);
    }
}

// ---------------- Gram MFMA bf16x2 + merged nm segment (blockIdx.z==2) ----------------
__global__ __launch_bounds__(256) void k_gram(const unsigned short* __restrict__ fH,
                                              const unsigned short* __restrict__ fL,
                                              const unsigned short* __restrict__ bH,
                                              const unsigned short* __restrict__ bL,
                                              float* __restrict__ GT,
                                              const float* __restrict__ ssq, const float* __restrict__ mask,
                                              float* __restrict__ norms, float* __restrict__ mmb) {
    if (blockIdx.z == 2) {                    // ---- nm segment (12 active blocks) ----
        int blk = blockIdx.y * 16 + blockIdx.x;
        if (blk >= 12) return;
        int idx = blk * 256 + threadIdx.x;    // 0..3071
        if (idx < 2048) {
            int q = idx & (Lq - 1);
            int bb = idx >> 10;
            int qy = q >> 5, qx = q & 31;
            float s = 0.1152f;
            for (int dk = -1; dk <= 1; ++dk) {
                int y = qy + dk; if ((unsigned)y >= (unsigned)HS) continue;
                for (int dl = -1; dl <= 1; ++dl) {
                    int x = qx + dl; if ((unsigned)x >= (unsigned)HS) continue;
                    s += ssq[bb * Lq + y * HS + x];
                }
            }
            norms[idx] = sqrtf(s);
        } else if (idx < 3072) {
            int q = idx - 2048;               // 0..1023
            int qy = q >> 5, qx = q & 31;
            float s = 0.f;
            for (int dk = -1; dk <= 1; ++dk) {
                int y = qy + dk; if ((unsigned)y >= (unsigned)HS) continue;
                for (int dl = -1; dl <= 1; ++dl) {
                    int x = qx + dl; if ((unsigned)x >= (unsigned)HS) continue;
                    s += mask[(8 * y) * 256 + 8 * x];
                }
            }
            mmb[q] = (s == 0.0f) ? 1.0f : 0.0f;
        }
        return;
    }
    const long bz = blockIdx.z;
    const unsigned short* AH = fH + bz * 131072;
    const unsigned short* AL = fL + bz * 131072;
    const unsigned short* BH = bH + bz * 131072;
    const unsigned short* BL = bL + bz * 131072;
    float* C = GT + (bz << 20);
    int t = threadIdx.x, w = t >> 6, lane = t & 63, quad = lane >> 4, l16 = lane & 15;
    int wm = blockIdx.x * 64 + (w & 1) * 32;
    int wn = blockIdx.y * 64 + (w >> 1) * 32;
    int ko = quad * 8;
    f32x4 acc[2][2] = {};
#pragma unroll
    for (int k0 = 0; k0 < 128; k0 += 32) {
        bf16x8 ah0 = *(const bf16x8*)&AH[(wm + l16) * 128 + ko + k0];
        bf16x8 ah1 = *(const bf16x8*)&AH[(wm + 16 + l16) * 128 + ko + k0];
        bf16x8 al0 = *(const bf16x8*)&AL[(wm + l16) * 128 + ko + k0];
        bf16x8 al1 = *(const bf16x8*)&AL[(wm + 16 + l16) * 128 + ko + k0];
        bf16x8 bh0 = *(const bf16x8*)&BH[(wn + l16) * 128 + ko + k0];
        bf16x8 bh1 = *(const bf16x8*)&BH[(wn + 16 + l16) * 128 + ko + k0];
        bf16x8 bl0 = *(const bf16x8*)&BL[(wn + l16) * 128 + ko + k0];
        bf16x8 bl1 = *(const bf16x8*)&BL[(wn + 16 + l16) * 128 + ko + k0];
        acc[0][0] = __builtin_amdgcn_mfma_f32_16x16x32_bf16(ah0, bh0, acc[0][0], 0, 0, 0);
        acc[0][1] = __builtin_amdgcn_mfma_f32_16x16x32_bf16(ah0, bh1, acc[0][1], 0, 0, 0);
        acc[1][0] = __builtin_amdgcn_mfma_f32_16x16x32_bf16(ah1, bh0, acc[1][0], 0, 0, 0);
        acc[1][1] = __builtin_amdgcn_mfma_f32_16x16x32_bf16(ah1, bh1, acc[1][1], 0, 0, 0);
        acc[0][0] = __builtin_amdgcn_mfma_f32_16x16x32_bf16(ah0, bl0, acc[0][0], 0, 0, 0);
        acc[0][1] = __builtin_amdgcn_mfma_f32_16x16x32_bf16(ah0, bl1, acc[0][1], 0, 0, 0);
        acc[1][0] = __builtin_amdgcn_mfma_f32_16x16x32_bf16(ah1, bl0, acc[1][0], 0, 0, 0);
        acc[1][1] = __builtin_amdgcn_mfma_f32_16x16x32_bf16(ah1, bl1, acc[1][1], 0, 0, 0);
        acc[0][0] = __builtin_amdgcn_mfma_f32_16x16x32_bf16(al0, bh0, acc[0][0], 0, 0, 0);
        acc[0][1] = __builtin_amdgcn_mfma_f32_16x16x32_bf16(al0, bh1, acc[0][1], 0, 0, 0);
        acc[1][0] = __builtin_amdgcn_mfma_f32_16x16x32_bf16(al1, bh0, acc[1][0], 0, 0, 0);
        acc[1][1] = __builtin_amdgcn_mfma_f32_16x16x32_bf16(al1, bh1, acc[1][1], 0, 0, 0);
    }
#pragma unroll
    for (int i = 0; i < 2; ++i)
#pragma unroll
        for (int j = 0; j < 2; ++j) {
            int mrow = wm + i * 16 + quad * 4;
            int ncol = wn + j * 16 + l16;
#pragma unroll
            for (int r = 0; r < 4; ++r)
                C[(long)(mrow + r) * Lq + ncol] = acc[i][j][r];
        }
}

// ---------------- S0T[p][q] = band9(GT) / norms[q]  (T-layout, r14-verified) ----------------
__global__ __launch_bounds__(256) void k_s0T(const float* __restrict__ GT, const float* __restrict__ norms,
                                             float* __restrict__ S0T) {
    int idx = blockIdx.x * 256 + threadIdx.x;  // 2*1024*1024
    int q  = idx & (Lq - 1);
    int pp = (idx >> 10) & (Lq - 1);
    int bb = idx >> 20;
    int qy = q >> 5, qx = q & 31, py = pp >> 5, px = pp & 31;
    const float* Gb = GT + ((long)bb << 20);
    float s = 0.f;
#pragma unroll
    for (int dk = -1; dk <= 1; ++dk) {
        if ((unsigned)(qy + dk) >= (unsigned)HS || (unsigned)(py + dk) >= (unsigned)HS) continue;
#pragma unroll
        for (int dl = -1; dl <= 1; ++dl) {
            if ((unsigned)(qx + dl) >= (unsigned)HS || (unsigned)(px + dl) >= (unsigned)HS) continue;
            int sft = dk * HS + dl;
            s += Gb[(long)(pp + sft) * Lq + (q + sft)];
        }
    }
    S0T[idx] = s / norms[bb * Lq + q];
}

// ---------------- FUSED fuse1+fuse2 on T layout (r14/r16-verified) ----------------
__global__ __launch_bounds__(256) void k_fuse12(const float* __restrict__ S0, float* __restrict__ S2) {
    int idx = blockIdx.x * 256 + threadIdx.x;   // 2*1024*1024
    int p  = idx & (Lq - 1);
    int q  = (idx >> 10) & (Lq - 1);
    int bb = idx >> 20;
    int hb = q >> 5, wb = q & 31, hf = p >> 5, wf = p & 31;
    int ip = wb * HS + hb, jp = wf * HS + hf;
    const float* S = S0 + (long)bb * Lq * Lq;
    float s = 0.f;
#pragma unroll
    for (int d = -1; d <= 1; ++d) {
        int t = ip + d, r = jp + d;
        if ((unsigned)t < (unsigned)Lq && (unsigned)r < (unsigned)Lq) {
            int q2 = (t & 31) * HS + (t >> 5);
            int p2 = (r & 31) * HS + (r >> 5);
            long base = (long)q2 * Lq + p2;
            float v = S[base];
            if (q2 > 0 && p2 > 0)             v += S[base - (Lq + 1)];
            if (q2 < Lq - 1 && p2 < Lq - 1)   v += S[base + (Lq + 1)];
            s += v;
        }
    }
    S2[idx] = s;
}

// ---------------- row softmax over q on S2T[p][q]; writes attnT bf16 [p][q] (r13-verified) ----------------
__global__ __launch_bounds__(256) void k_softmaxT(const float* __restrict__ S2T, const float* __restrict__ mmb,
                                                  unsigned short* __restrict__ At) {
    int wid = blockIdx.x * 4 + (threadIdx.x >> 6);   // 0..2047
    int lane = threadIdx.x & 63;
    int bb = wid >> 10, p = wid & (Lq - 1);
    const float* row = S2T + ((long)bb << 20) + (long)p * Lq;
    unsigned short* orow = At + ((long)bb << 20) + (long)p * Lq;
    float x[16]; float mx = -1e30f;
#pragma unroll
    for (int i = 0; i < 16; ++i) {
        int q = i * 64 + lane;
        x[i] = row[q] * mmb[q] * 10.0f;
        mx = fmaxf(mx, x[i]);
    }
    for (int off = 32; off > 0; off >>= 1) mx = fmaxf(mx, __shfl_xor(mx, off, 64));
    float e[16]; float s = 0.f;
#pragma unroll
    for (int i = 0; i < 16; ++i) { e[i] = __expf(x[i] - mx); s += e[i]; }
    for (int off = 32; off > 0; off >>= 1) s += __shfl_xor(s, off, 64);
    float inv = 1.0f / s;
#pragma unroll
    for (int i = 0; i < 16; ++i) {
        int q = i * 64 + lane;
        orow[q] = f2bf(e[i] * mmb[q] * inv);
    }
}

// ---------------- MFMA GEMM: 64x64 tile, counted-vmcnt 2-deep pipeline, XOR swizzle ----------------
// P[m][p] = sum_q Wm[m][q]*attnT[p][q]. BM=64, BN=64, BK=64, grid (32,16,2) = 4 blocks/CU.
__global__ __launch_bounds__(256) void k_gemm_mfma(const unsigned short* __restrict__ WmA,
                                                   const unsigned short* __restrict__ At,
                                                   float* __restrict__ Cm) {
    const long bz = blockIdx.z;
    const unsigned short* A = WmA + bz * (2048L * Lq);
    const unsigned short* B = At  + bz * ((long)Lq * Lq);
    float* C = Cm + bz * (2048L * Lq);
    __shared__ __align__(16) unsigned short As0[64 * 64], As1[64 * 64];  // 8 KB each
    __shared__ __align__(16) unsigned short Bs0[64 * 64], Bs1[64 * 64];  // 32 KB total
    int t = threadIdx.x;
    int w = t >> 6, lane = t & 63, quad = lane >> 4, l16 = lane & 15;
    int wr = w >> 1, wc = w & 1;             // 2x2 wave grid; wave tile 32x32
    int m0 = blockIdx.x * 64, n0 = blockIdx.y * 64;
    int srow  = t >> 3;                       // 0..31: row within a 32-row staging round
    int scolS = ((t & 7) ^ ((t >> 3) & 7)) << 3;  // pre-swizzled global source col (elems)
    int sdst  = t * 8;                        // linear LDS dest (elems) = t*16 bytes
    int xr    = l16 & 7;                      // read-side row XOR key
    f32x4 acc[2][2] = {};

#define STG(AS, BS, kk) do {                                                        \
    _Pragma("unroll")                                                               \
    for (int r = 0; r < 2; ++r)  /* A: 64 rows = 2 rounds */                        \
        gload16(A + (long)(m0 + r * 32 + srow) * Lq + (kk) + scolS,                 \
                &AS[r * 2048 + sdst]);                                              \
    _Pragma("unroll")                                                               \
    for (int r = 0; r < 2; ++r)  /* B: 64 rows = 2 rounds */                        \
        gload16(B + (long)(n0 + r * 32 + srow) * Lq + (kk) + scolS,                 \
                &BS[r * 2048 + sdst]);                                              \
} while (0)

#define CMP(AS, BS) do {                                                            \
    _Pragma("unroll")                                                               \
    for (int ks = 0; ks < 2; ++ks) {                                                \
        int slot = ((ks * 4 + quad) ^ xr) << 3;                                     \
        bf16x8 a0 = *(const bf16x8*)&AS[(wr * 32 +      l16) * 64 + slot];          \
        bf16x8 a1 = *(const bf16x8*)&AS[(wr * 32 + 16 + l16) * 64 + slot];          \
        bf16x8 b0 = *(const bf16x8*)&BS[(wc * 32 +      l16) * 64 + slot];          \
        bf16x8 b1 = *(const bf16x8*)&BS[(wc * 32 + 16 + l16) * 64 + slot];          \
        acc[0][0] = __builtin_amdgcn_mfma_f32_16x16x32_bf16(a0, b0, acc[0][0], 0, 0, 0); \
        acc[0][1] = __builtin_amdgcn_mfma_f32_16x16x32_bf16(a0, b1, acc[0][1], 0, 0, 0); \
        acc[1][0] = __builtin_amdgcn_mfma_f32_16x16x32_bf16(a1, b0, acc[1][0], 0, 0, 0); \
        acc[1][1] = __builtin_amdgcn_mfma_f32_16x16x32_bf16(a1, b1, acc[1][1], 0, 0, 0); \
    }                                                                               \
} while (0)

#define SBAR() do { __builtin_amdgcn_s_barrier(); asm volatile("" ::: "memory"); } while (0)
#define WAITV4() do { asm volatile("s_waitcnt vmcnt(4)" ::: "memory"); __builtin_amdgcn_sched_barrier(0); } while (0)
#define WAITV0() do { asm volatile("s_waitcnt vmcnt(0)" ::: "memory"); __builtin_amdgcn_sched_barrier(0); } while (0)

    STG(As0, Bs0, 0);                         // tile 0: 4 loads in flight
    STG(As1, Bs1, 64);                        // tile 1: 8 in flight
    for (int k0 = 0; k0 < Lq; k0 += 128) {
        WAITV4();                             // oldest 4 (As0/Bs0 tile) landed
        SBAR();                               // all waves see it
        CMP(As0, Bs0);
        SBAR();                               // all waves done reading As0/Bs0
        if (k0 + 128 < Lq) STG(As0, Bs0, k0 + 128);   // 2 tiles ahead; back to 8 in flight
        if (k0 + 128 < Lq) WAITV4(); else WAITV0();   // As1/Bs1 tile landed
        SBAR();
        CMP(As1, Bs1);
        SBAR();
        if (k0 + 192 < Lq) STG(As1, Bs1, k0 + 192);
    }
#undef STG
#undef CMP
#undef SBAR
#undef WAITV4
#undef WAITV0
#pragma unroll
    for (int i = 0; i < 2; ++i) {
        int mrow = m0 + wr * 32 + i * 16 + quad * 4;
#pragma unroll
        for (int j = 0; j < 2; ++j) {
            int ncol = n0 + wc * 32 + j * 16 + l16;
#pragma unroll
            for (int r = 0; r < 4; ++r)
                C[(long)(mrow + r) * Lq + ncol] = acc[i][j][r];
        }
    }
}

// ---------------- literal conv epilogue: fp32 tap-sum, /4, store fp32 (r11-verified) ----------------
__global__ __launch_bounds__(256) void k_epi2(const float* __restrict__ P, float* __restrict__ out) {
    int idx = blockIdx.x * 256 + threadIdx.x;   // 1048576
    int ox = idx & 63, oy = (idx >> 6) & 63, c = (idx >> 12) & 127, bb = idx >> 19;
    const float* Pb = P + (long)bb * 2048 * Lq;
    float s = 0.f;
#pragma unroll
    for (int u = 0; u < 4; ++u) {
        int t = oy + u - 2;
        if (t & 1) continue;
        int iy = t >> 1;
        if ((unsigned)iy >= (unsigned)HS) continue;
#pragma unroll
        for (int v = 0; v < 4; ++v) {
            int r = ox + v - 2;
            if (r & 1) continue;
            int ix = r >> 1;
            if ((unsigned)ix >= (unsigned)HS) continue;
            s += Pb[(long)((c << 4) + (3 - u) * 4 + (3 - v)) * Lq + (iy << 5) + ix];
        }
    }
    out[idx] = 0.25f * s;
}

extern "C" void kernel_launch(void* const* d_in, const int* in_sizes, int n_in,
                              void* d_out, int out_size, void* d_ws, size_t ws_size,
                              hipStream_t stream) {
    const float* f    = (const float*)d_in[0];
    const float* bsrc = (const float*)d_in[1];
    const float* mask = (const float*)d_in[2];
    float* out = (float*)d_out;
    float* ws = (float*)d_ws;

    // workspace (floats): ~8.9M = 35.7 MB
    float* ssq   = ws;                        // 2048
    float* norms = ssq   + 2048;              // 2048
    float* mmb   = norms + 2048;              // 1024
    unsigned short* fH = (unsigned short*)(mmb + 1024);      // 262144 ushorts each
    unsigned short* fL = fH + 262144;
    unsigned short* bH = fL + 262144;
    unsigned short* bL = bH + 262144;
    float* GTa   = (float*)(bL + 262144);     // 2097152 : GT -> attnT(bf16)
    float* C1    = GTa + 2097152;             // 2097152 : S0T -> P[0:2M]
    float* C2    = C1  + 2097152;             // 2097152 : S2T -> P[2M:4M]
    unsigned short* Wm = (unsigned short*)(C2 + 2097152);    // 4194304 ushorts
    float* S0T  = C1;
    float* S2T  = C2;
    unsigned short* attnT = (unsigned short*)GTa;  // GT dead after k_s0T
    float* P    = C1;      // spans C1+C2; S0T dead after fuse12, S2T dead after softmax

    hipLaunchKernelGGL(k_prep3,     dim3(16896),      dim3(256), 0, stream, f, bsrc, fH, fL, bH, bL, ssq, Wm);
    hipLaunchKernelGGL(k_gram,      dim3(16, 16, 3),  dim3(256), 0, stream, fH, fL, bH, bL, GTa, ssq, mask, norms, mmb);
    hipLaunchKernelGGL(k_s0T,       dim3(8192),       dim3(256), 0, stream, GTa, norms, S0T);
    hipLaunchKernelGGL(k_fuse12,    dim3(8192),       dim3(256), 0, stream, S0T, S2T);
    hipLaunchKernelGGL(k_softmaxT,  dim3(512),        dim3(256), 0, stream, S2T, mmb, attnT);
    hipLaunchKernelGGL(k_gemm_mfma, dim3(32, 16, 2),  dim3(256), 0, stream, Wm, attnT, P);
    hipLaunchKernelGGL(k_gemm_mfma, dim3(32, 16, 2),  dim3(256), 0, stream, Wm, attnT, P);  // ABLATION: 2nd identical launch
    hipLaunchKernelGGL(k_epi2,      dim3(4096),       dim3(256), 0, stream, P, out);
}

// Round 11
// 135.509 us; speedup vs baseline: 1.1167x; 1.1167x over previous
//
#include <hip/hip_runtime.h>
#include <hip/hip_bf16.h>
#include <math.h>

constexpr int HS = 32;      // half spatial (32x32 grids)
constexpr int Lq = 1024;    // HS*HS
constexpr int CN = 128;     // channels
// batches = 2. Inputs fp32 (f, b, mask). Output fp32 (r11-verified).
// R29: ablation (r28) measured gemm = 15.0us marginal (~570 TF, 64^2-tile ceiling).
// Pre-committed action: 128x64 tile with STATIC dbuf (r25 fix) + XOR swizzle (r24)
// + counted-vmcnt(6) 2-tile pipeline (r27 discipline; 6 loads/stage now).
// MFMA:ds ratio 16:12 vs 8:8, B-fetch halved. K order identical -> bit-identical C,
// absmax exactly 0.015625. All other kernels byte-identical to r27 (136.35 best).

typedef short bf16x8 __attribute__((ext_vector_type(8)));
typedef float f32x4  __attribute__((ext_vector_type(4)));

__device__ inline unsigned short f2bf(float x) {   // RNE float->bf16 bits
    union { float f; unsigned int u; } c; c.f = x;
    return (unsigned short)((c.u + 0x7FFF + ((c.u >> 16) & 1)) >> 16);
}
__device__ inline float bf2f(unsigned short h) {
    union { unsigned int u; float f; } c; c.u = ((unsigned int)h) << 16;
    return c.f;
}

// async global->LDS, 16B per lane (wave-uniform LDS base + lane*16 layout)
__device__ inline void gload16(const void* g, void* l) {
    __builtin_amdgcn_global_load_lds(
        (const __attribute__((address_space(1))) unsigned int*)g,
        (__attribute__((address_space(3))) unsigned int*)l, 16, 0, 0);
}

// ---------------- merged prep+ssq+wm: one launch, two grid segments ----------------
__global__ __launch_bounds__(256) void k_prep3(const float* __restrict__ f,
                                               const float* __restrict__ bsrc,
                                               unsigned short* __restrict__ fH, unsigned short* __restrict__ fL,
                                               unsigned short* __restrict__ bH, unsigned short* __restrict__ bL,
                                               float* __restrict__ ssq,
                                               unsigned short* __restrict__ Wm) {
    int tx = threadIdx.x;
    if (blockIdx.x < 512) {
        int u = blockIdx.x * 4 + (tx >> 6);  // 0..2047 = bb*1024 + p
        int lane = tx & 63;
        int p = u & (Lq - 1), bb = u >> 10;
        int py = p >> 5, px = p & 31;
        long srcbase = (((long)bb * CN) * 64 + 2 * py) * 64 + 2 * px;
        float s = 0.f;
#pragma unroll
        for (int i = 0; i < 2; ++i) {
            int c = lane + i * 64;
            long src = srcbase + (long)c * 4096;
            float fv = f[src], bv = bsrc[src];
            int o = u * CN + c;
            unsigned short fh = f2bf(fv), bh = f2bf(bv);
            fH[o] = fh; fL[o] = f2bf(fv - bf2f(fh));
            bH[o] = bh; bL[o] = f2bf(bv - bf2f(bh));
            s += bv * bv;
        }
        for (int off = 32; off > 0; off >>= 1) s += __shfl_down(s, off, 64);
        if (lane == 0) ssq[u] = s;
    } else {
        int idx = (blockIdx.x - 512) * 256 + tx;   // 2*2048*1024
        int q  = idx & (Lq - 1);
        int m  = (idx >> 10) & 2047;
        int bb = idx >> 21;
        int c = m >> 4, u = (m >> 2) & 3, v = m & 3;
        int qy = q >> 5, qx = q & 31;
        int y = 2 * qy + u - 1, x = 2 * qx + v - 1;
        float val = 0.f;
        if ((unsigned)y < 64u && (unsigned)x < 64u)
            val = bsrc[(((long)bb * CN + c) * 64 + y) * 64 + x];
        Wm[idx] = f2bf(val);
    }
}

// ---------------- Gram MFMA bf16x2 + merged nm segment (blockIdx.z==2) ----------------
__global__ __launch_bounds__(256) void k_gram(const unsigned short* __restrict__ fH,
                                              const unsigned short* __restrict__ fL,
                                              const unsigned short* __restrict__ bH,
                                              const unsigned short* __restrict__ bL,
                                              float* __restrict__ GT,
                                              const float* __restrict__ ssq, const float* __restrict__ mask,
                                              float* __restrict__ norms, float* __restrict__ mmb) {
    if (blockIdx.z == 2) {                    // ---- nm segment (12 active blocks) ----
        int blk = blockIdx.y * 16 + blockIdx.x;
        if (blk >= 12) return;
        int idx = blk * 256 + threadIdx.x;    // 0..3071
        if (idx < 2048) {
            int q = idx & (Lq - 1);
            int bb = idx >> 10;
            int qy = q >> 5, qx = q & 31;
            float s = 0.1152f;
            for (int dk = -1; dk <= 1; ++dk) {
                int y = qy + dk; if ((unsigned)y >= (unsigned)HS) continue;
                for (int dl = -1; dl <= 1; ++dl) {
                    int x = qx + dl; if ((unsigned)x >= (unsigned)HS) continue;
                    s += ssq[bb * Lq + y * HS + x];
                }
            }
            norms[idx] = sqrtf(s);
        } else if (idx < 3072) {
            int q = idx - 2048;               // 0..1023
            int qy = q >> 5, qx = q & 31;
            float s = 0.f;
            for (int dk = -1; dk <= 1; ++dk) {
                int y = qy + dk; if ((unsigned)y >= (unsigned)HS) continue;
                for (int dl = -1; dl <= 1; ++dl) {
                    int x = qx + dl; if ((unsigned)x >= (unsigned)HS) continue;
                    s += mask[(8 * y) * 256 + 8 * x];
                }
            }
            mmb[q] = (s == 0.0f) ? 1.0f : 0.0f;
        }
        return;
    }
    const long bz = blockIdx.z;
    const unsigned short* AH = fH + bz * 131072;
    const unsigned short* AL = fL + bz * 131072;
    const unsigned short* BH = bH + bz * 131072;
    const unsigned short* BL = bL + bz * 131072;
    float* C = GT + (bz << 20);
    int t = threadIdx.x, w = t >> 6, lane = t & 63, quad = lane >> 4, l16 = lane & 15;
    int wm = blockIdx.x * 64 + (w & 1) * 32;
    int wn = blockIdx.y * 64 + (w >> 1) * 32;
    int ko = quad * 8;
    f32x4 acc[2][2] = {};
#pragma unroll
    for (int k0 = 0; k0 < 128; k0 += 32) {
        bf16x8 ah0 = *(const bf16x8*)&AH[(wm + l16) * 128 + ko + k0];
        bf16x8 ah1 = *(const bf16x8*)&AH[(wm + 16 + l16) * 128 + ko + k0];
        bf16x8 al0 = *(const bf16x8*)&AL[(wm + l16) * 128 + ko + k0];
        bf16x8 al1 = *(const bf16x8*)&AL[(wm + 16 + l16) * 128 + ko + k0];
        bf16x8 bh0 = *(const bf16x8*)&BH[(wn + l16) * 128 + ko + k0];
        bf16x8 bh1 = *(const bf16x8*)&BH[(wn + 16 + l16) * 128 + ko + k0];
        bf16x8 bl0 = *(const bf16x8*)&BL[(wn + l16) * 128 + ko + k0];
        bf16x8 bl1 = *(const bf16x8*)&BL[(wn + 16 + l16) * 128 + ko + k0];
        acc[0][0] = __builtin_amdgcn_mfma_f32_16x16x32_bf16(ah0, bh0, acc[0][0], 0, 0, 0);
        acc[0][1] = __builtin_amdgcn_mfma_f32_16x16x32_bf16(ah0, bh1, acc[0][1], 0, 0, 0);
        acc[1][0] = __builtin_amdgcn_mfma_f32_16x16x32_bf16(ah1, bh0, acc[1][0], 0, 0, 0);
        acc[1][1] = __builtin_amdgcn_mfma_f32_16x16x32_bf16(ah1, bh1, acc[1][1], 0, 0, 0);
        acc[0][0] = __builtin_amdgcn_mfma_f32_16x16x32_bf16(ah0, bl0, acc[0][0], 0, 0, 0);
        acc[0][1] = __builtin_amdgcn_mfma_f32_16x16x32_bf16(ah0, bl1, acc[0][1], 0, 0, 0);
        acc[1][0] = __builtin_amdgcn_mfma_f32_16x16x32_bf16(ah1, bl0, acc[1][0], 0, 0, 0);
        acc[1][1] = __builtin_amdgcn_mfma_f32_16x16x32_bf16(ah1, bl1, acc[1][1], 0, 0, 0);
        acc[0][0] = __builtin_amdgcn_mfma_f32_16x16x32_bf16(al0, bh0, acc[0][0], 0, 0, 0);
        acc[0][1] = __builtin_amdgcn_mfma_f32_16x16x32_bf16(al0, bh1, acc[0][1], 0, 0, 0);
        acc[1][0] = __builtin_amdgcn_mfma_f32_16x16x32_bf16(al1, bh0, acc[1][0], 0, 0, 0);
        acc[1][1] = __builtin_amdgcn_mfma_f32_16x16x32_bf16(al1, bh1, acc[1][1], 0, 0, 0);
    }
#pragma unroll
    for (int i = 0; i < 2; ++i)
#pragma unroll
        for (int j = 0; j < 2; ++j) {
            int mrow = wm + i * 16 + quad * 4;
            int ncol = wn + j * 16 + l16;
#pragma unroll
            for (int r = 0; r < 4; ++r)
                C[(long)(mrow + r) * Lq + ncol] = acc[i][j][r];
        }
}

// ---------------- S0T[p][q] = band9(GT) / norms[q]  (T-layout, r14-verified) ----------------
__global__ __launch_bounds__(256) void k_s0T(const float* __restrict__ GT, const float* __restrict__ norms,
                                             float* __restrict__ S0T) {
    int idx = blockIdx.x * 256 + threadIdx.x;  // 2*1024*1024
    int q  = idx & (Lq - 1);
    int pp = (idx >> 10) & (Lq - 1);
    int bb = idx >> 20;
    int qy = q >> 5, qx = q & 31, py = pp >> 5, px = pp & 31;
    const float* Gb = GT + ((long)bb << 20);
    float s = 0.f;
#pragma unroll
    for (int dk = -1; dk <= 1; ++dk) {
        if ((unsigned)(qy + dk) >= (unsigned)HS || (unsigned)(py + dk) >= (unsigned)HS) continue;
#pragma unroll
        for (int dl = -1; dl <= 1; ++dl) {
            if ((unsigned)(qx + dl) >= (unsigned)HS || (unsigned)(px + dl) >= (unsigned)HS) continue;
            int sft = dk * HS + dl;
            s += Gb[(long)(pp + sft) * Lq + (q + sft)];
        }
    }
    S0T[idx] = s / norms[bb * Lq + q];
}

// ---------------- FUSED fuse1+fuse2 on T layout (r14/r16-verified) ----------------
__global__ __launch_bounds__(256) void k_fuse12(const float* __restrict__ S0, float* __restrict__ S2) {
    int idx = blockIdx.x * 256 + threadIdx.x;   // 2*1024*1024
    int p  = idx & (Lq - 1);
    int q  = (idx >> 10) & (Lq - 1);
    int bb = idx >> 20;
    int hb = q >> 5, wb = q & 31, hf = p >> 5, wf = p & 31;
    int ip = wb * HS + hb, jp = wf * HS + hf;
    const float* S = S0 + (long)bb * Lq * Lq;
    float s = 0.f;
#pragma unroll
    for (int d = -1; d <= 1; ++d) {
        int t = ip + d, r = jp + d;
        if ((unsigned)t < (unsigned)Lq && (unsigned)r < (unsigned)Lq) {
            int q2 = (t & 31) * HS + (t >> 5);
            int p2 = (r & 31) * HS + (r >> 5);
            long base = (long)q2 * Lq + p2;
            float v = S[base];
            if (q2 > 0 && p2 > 0)             v += S[base - (Lq + 1)];
            if (q2 < Lq - 1 && p2 < Lq - 1)   v += S[base + (Lq + 1)];
            s += v;
        }
    }
    S2[idx] = s;
}

// ---------------- row softmax over q on S2T[p][q]; writes attnT bf16 [p][q] (r13-verified) ----------------
__global__ __launch_bounds__(256) void k_softmaxT(const float* __restrict__ S2T, const float* __restrict__ mmb,
                                                  unsigned short* __restrict__ At) {
    int wid = blockIdx.x * 4 + (threadIdx.x >> 6);   // 0..2047
    int lane = threadIdx.x & 63;
    int bb = wid >> 10, p = wid & (Lq - 1);
    const float* row = S2T + ((long)bb << 20) + (long)p * Lq;
    unsigned short* orow = At + ((long)bb << 20) + (long)p * Lq;
    float x[16]; float mx = -1e30f;
#pragma unroll
    for (int i = 0; i < 16; ++i) {
        int q = i * 64 + lane;
        x[i] = row[q] * mmb[q] * 10.0f;
        mx = fmaxf(mx, x[i]);
    }
    for (int off = 32; off > 0; off >>= 1) mx = fmaxf(mx, __shfl_xor(mx, off, 64));
    float e[16]; float s = 0.f;
#pragma unroll
    for (int i = 0; i < 16; ++i) { e[i] = __expf(x[i] - mx); s += e[i]; }
    for (int off = 32; off > 0; off >>= 1) s += __shfl_xor(s, off, 64);
    float inv = 1.0f / s;
#pragma unroll
    for (int i = 0; i < 16; ++i) {
        int q = i * 64 + lane;
        orow[q] = f2bf(e[i] * mmb[q] * inv);
    }
}

// ---------------- MFMA GEMM: 128x64 tile, STATIC dbuf, counted vmcnt(6), XOR swizzle ----------------
// P[m][p] = sum_q Wm[m][q]*attnT[p][q]. BM=128, BN=64, BK=64, grid (16,16,2) = 2 blocks/CU.
// LDS 48KB: As0/As1 16KB + Bs0/Bs1 8KB. 6 gload16/thread/stage; 2 tiles (12 loads) in
// flight; s_waitcnt vmcnt(6) per tile (never 0 mid-loop). Wave tile 64x32, acc[4][2].
// K order identical to r19/r24/r27 -> bit-identical C.
__global__ __launch_bounds__(256) void k_gemm_mfma(const unsigned short* __restrict__ WmA,
                                                   const unsigned short* __restrict__ At,
                                                   float* __restrict__ Cm) {
    const long bz = blockIdx.z;
    const unsigned short* A = WmA + bz * (2048L * Lq);
    const unsigned short* B = At  + bz * ((long)Lq * Lq);
    float* C = Cm + bz * (2048L * Lq);
    __shared__ __align__(16) unsigned short As0[128 * 64], As1[128 * 64];  // 16 KB each
    __shared__ __align__(16) unsigned short Bs0[64 * 64],  Bs1[64 * 64];   //  8 KB each
    int t = threadIdx.x;
    int w = t >> 6, lane = t & 63, quad = lane >> 4, l16 = lane & 15;
    int wr = w >> 1, wc = w & 1;             // wave tile: rows wr*64.., cols wc*32..
    int m0 = blockIdx.x * 128, n0 = blockIdx.y * 64;
    int srow  = t >> 3;                       // 0..31: row within a 32-row staging round
    int scolS = ((t & 7) ^ ((t >> 3) & 7)) << 3;  // pre-swizzled global source col (elems)
    int sdst  = t * 8;                        // linear LDS dest (elems) = t*16 bytes
    int xr    = l16 & 7;                      // read-side row XOR key
    f32x4 acc[4][2] = {};

#define STG(AS, BS, kk) do {                                                        \
    _Pragma("unroll")                                                               \
    for (int r = 0; r < 4; ++r)  /* A: 128 rows = 4 rounds */                       \
        gload16(A + (long)(m0 + r * 32 + srow) * Lq + (kk) + scolS,                 \
                &AS[r * 2048 + sdst]);                                              \
    _Pragma("unroll")                                                               \
    for (int r = 0; r < 2; ++r)  /* B: 64 rows = 2 rounds */                        \
        gload16(B + (long)(n0 + r * 32 + srow) * Lq + (kk) + scolS,                 \
                &BS[r * 2048 + sdst]);                                              \
} while (0)

#define CMP(AS, BS) do {                                                            \
    _Pragma("unroll")                                                               \
    for (int ks = 0; ks < 2; ++ks) {                                                \
        int slot = ((ks * 4 + quad) ^ xr) << 3;                                     \
        bf16x8 a[4], b[2];                                                          \
        _Pragma("unroll")                                                           \
        for (int i = 0; i < 4; ++i)                                                 \
            a[i] = *(const bf16x8*)&AS[(wr * 64 + i * 16 + l16) * 64 + slot];       \
        _Pragma("unroll")                                                           \
        for (int j = 0; j < 2; ++j)                                                 \
            b[j] = *(const bf16x8*)&BS[(wc * 32 + j * 16 + l16) * 64 + slot];       \
        _Pragma("unroll")                                                           \
        for (int i = 0; i < 4; ++i)                                                 \
            _Pragma("unroll")                                                       \
            for (int j = 0; j < 2; ++j)                                             \
                acc[i][j] = __builtin_amdgcn_mfma_f32_16x16x32_bf16(a[i], b[j], acc[i][j], 0, 0, 0); \
    }                                                                               \
} while (0)

#define SBAR() do { __builtin_amdgcn_s_barrier(); asm volatile("" ::: "memory"); } while (0)
#define WAITV6() do { asm volatile("s_waitcnt vmcnt(6)" ::: "memory"); __builtin_amdgcn_sched_barrier(0); } while (0)
#define WAITV0() do { asm volatile("s_waitcnt vmcnt(0)" ::: "memory"); __builtin_amdgcn_sched_barrier(0); } while (0)

    STG(As0, Bs0, 0);                         // tile 0: 6 loads in flight
    STG(As1, Bs1, 64);                        // tile 1: 12 in flight
    for (int k0 = 0; k0 < Lq; k0 += 128) {
        WAITV6();                             // oldest 6 (As0/Bs0 tile) landed
        SBAR();
        CMP(As0, Bs0);
        SBAR();
        if (k0 + 128 < Lq) STG(As0, Bs0, k0 + 128);   // back to 12 in flight
        if (k0 + 128 < Lq) WAITV6(); else WAITV0();   // As1/Bs1 tile landed
        SBAR();
        CMP(As1, Bs1);
        SBAR();
        if (k0 + 192 < Lq) STG(As1, Bs1, k0 + 192);
    }
#undef STG
#undef CMP
#undef SBAR
#undef WAITV6
#undef WAITV0
#pragma unroll
    for (int i = 0; i < 4; ++i) {
        int mrow = m0 + wr * 64 + i * 16 + quad * 4;
#pragma unroll
        for (int j = 0; j < 2; ++j) {
            int ncol = n0 + wc * 32 + j * 16 + l16;
#pragma unroll
            for (int r = 0; r < 4; ++r)
                C[(long)(mrow + r) * Lq + ncol] = acc[i][j][r];
        }
    }
}

// ---------------- literal conv epilogue: fp32 tap-sum, /4, store fp32 (r11-verified) ----------------
__global__ __launch_bounds__(256) void k_epi2(const float* __restrict__ P, float* __restrict__ out) {
    int idx = blockIdx.x * 256 + threadIdx.x;   // 1048576
    int ox = idx & 63, oy = (idx >> 6) & 63, c = (idx >> 12) & 127, bb = idx >> 19;
    const float* Pb = P + (long)bb * 2048 * Lq;
    float s = 0.f;
#pragma unroll
    for (int u = 0; u < 4; ++u) {
        int t = oy + u - 2;
        if (t & 1) continue;
        int iy = t >> 1;
        if ((unsigned)iy >= (unsigned)HS) continue;
#pragma unroll
        for (int v = 0; v < 4; ++v) {
            int r = ox + v - 2;
            if (r & 1) continue;
            int ix = r >> 1;
            if ((unsigned)ix >= (unsigned)HS) continue;
            s += Pb[(long)((c << 4) + (3 - u) * 4 + (3 - v)) * Lq + (iy << 5) + ix];
        }
    }
    out[idx] = 0.25f * s;
}

extern "C" void kernel_launch(void* const* d_in, const int* in_sizes, int n_in,
                              void* d_out, int out_size, void* d_ws, size_t ws_size,
                              hipStream_t stream) {
    const float* f    = (const float*)d_in[0];
    const float* bsrc = (const float*)d_in[1];
    const float* mask = (const float*)d_in[2];
    float* out = (float*)d_out;
    float* ws = (float*)d_ws;

    // workspace (floats): ~8.9M = 35.7 MB
    float* ssq   = ws;                        // 2048
    float* norms = ssq   + 2048;              // 2048
    float* mmb   = norms + 2048;              // 1024
    unsigned short* fH = (unsigned short*)(mmb + 1024);      // 262144 ushorts each
    unsigned short* fL = fH + 262144;
    unsigned short* bH = fL + 262144;
    unsigned short* bL = bH + 262144;
    float* GTa   = (float*)(bL + 262144);     // 2097152 : GT -> attnT(bf16)
    float* C1    = GTa + 2097152;             // 2097152 : S0T -> P[0:2M]
    float* C2    = C1  + 2097152;             // 2097152 : S2T -> P[2M:4M]
    unsigned short* Wm = (unsigned short*)(C2 + 2097152);    // 4194304 ushorts
    float* S0T  = C1;
    float* S2T  = C2;
    unsigned short* attnT = (unsigned short*)GTa;  // GT dead after k_s0T
    float* P    = C1;      // spans C1+C2; S0T dead after fuse12, S2T dead after softmax

    hipLaunchKernelGGL(k_prep3,     dim3(16896),      dim3(256), 0, stream, f, bsrc, fH, fL, bH, bL, ssq, Wm);
    hipLaunchKernelGGL(k_gram,      dim3(16, 16, 3),  dim3(256), 0, stream, fH, fL, bH, bL, GTa, ssq, mask, norms, mmb);
    hipLaunchKernelGGL(k_s0T,       dim3(8192),       dim3(256), 0, stream, GTa, norms, S0T);
    hipLaunchKernelGGL(k_fuse12,    dim3(8192),       dim3(256), 0, stream, S0T, S2T);
    hipLaunchKernelGGL(k_softmaxT,  dim3(512),        dim3(256), 0, stream, S2T, mmb, attnT);
    hipLaunchKernelGGL(k_gemm_mfma, dim3(16, 16, 2),  dim3(256), 0, stream, Wm, attnT, P);
    hipLaunchKernelGGL(k_epi2,      dim3(4096),       dim3(256), 0, stream, P, out);
}

// Round 12
// 131.731 us; speedup vs baseline: 1.1487x; 1.0287x over previous
//
#include <hip/hip_runtime.h>
#include <hip/hip_bf16.h>
#include <math.h>

constexpr int HS = 32;      // half spatial (32x32 grids)
constexpr int Lq = 1024;    // HS*HS
constexpr int CN = 128;     // channels
// batches = 2. Inputs fp32 (f, b, mask). Output fp32 (r11-verified).
// R30: fuse softmax INTO fuse12 (k_fuse12sm): fuse12's q (softmax row) is block-uniform;
// one 256-thr block now computes a full 1024-col row (4 vals/thread), LDS cross-wave
// reduce, writes attnT bf16 directly. Removes 1 launch + S2T 8MB write + 8MB read.
// Per-output fuse12 arithmetic order IDENTICAL; softmax denominator reduce order changes
// (~1e-7 rel; inside bf16-floor tolerance). gemm = r29 128x64 (saturated at ~14us:
// 48.8->15 via swizzle+dbuf, tile/pipeline now <1us returns — chapter closed).
// prep3/gram/s0T/epi2 byte-identical to r29 (135.5 best).

typedef short bf16x8 __attribute__((ext_vector_type(8)));
typedef float f32x4  __attribute__((ext_vector_type(4)));

__device__ inline unsigned short f2bf(float x) {   // RNE float->bf16 bits
    union { float f; unsigned int u; } c; c.f = x;
    return (unsigned short)((c.u + 0x7FFF + ((c.u >> 16) & 1)) >> 16);
}
__device__ inline float bf2f(unsigned short h) {
    union { unsigned int u; float f; } c; c.u = ((unsigned int)h) << 16;
    return c.f;
}

// async global->LDS, 16B per lane (wave-uniform LDS base + lane*16 layout)
__device__ inline void gload16(const void* g, void* l) {
    __builtin_amdgcn_global_load_lds(
        (const __attribute__((address_space(1))) unsigned int*)g,
        (__attribute__((address_space(3))) unsigned int*)l, 16, 0, 0);
}

// ---------------- merged prep+ssq+wm: one launch, two grid segments ----------------
__global__ __launch_bounds__(256) void k_prep3(const float* __restrict__ f,
                                               const float* __restrict__ bsrc,
                                               unsigned short* __restrict__ fH, unsigned short* __restrict__ fL,
                                               unsigned short* __restrict__ bH, unsigned short* __restrict__ bL,
                                               float* __restrict__ ssq,
                                               unsigned short* __restrict__ Wm) {
    int tx = threadIdx.x;
    if (blockIdx.x < 512) {
        int u = blockIdx.x * 4 + (tx >> 6);  // 0..2047 = bb*1024 + p
        int lane = tx & 63;
        int p = u & (Lq - 1), bb = u >> 10;
        int py = p >> 5, px = p & 31;
        long srcbase = (((long)bb * CN) * 64 + 2 * py) * 64 + 2 * px;
        float s = 0.f;
#pragma unroll
        for (int i = 0; i < 2; ++i) {
            int c = lane + i * 64;
            long src = srcbase + (long)c * 4096;
            float fv = f[src], bv = bsrc[src];
            int o = u * CN + c;
            unsigned short fh = f2bf(fv), bh = f2bf(bv);
            fH[o] = fh; fL[o] = f2bf(fv - bf2f(fh));
            bH[o] = bh; bL[o] = f2bf(bv - bf2f(bh));
            s += bv * bv;
        }
        for (int off = 32; off > 0; off >>= 1) s += __shfl_down(s, off, 64);
        if (lane == 0) ssq[u] = s;
    } else {
        int idx = (blockIdx.x - 512) * 256 + tx;   // 2*2048*1024
        int q  = idx & (Lq - 1);
        int m  = (idx >> 10) & 2047;
        int bb = idx >> 21;
        int c = m >> 4, u = (m >> 2) & 3, v = m & 3;
        int qy = q >> 5, qx = q & 31;
        int y = 2 * qy + u - 1, x = 2 * qx + v - 1;
        float val = 0.f;
        if ((unsigned)y < 64u && (unsigned)x < 64u)
            val = bsrc[(((long)bb * CN + c) * 64 + y) * 64 + x];
        Wm[idx] = f2bf(val);
    }
}

// ---------------- Gram MFMA bf16x2 + merged nm segment (blockIdx.z==2) ----------------
__global__ __launch_bounds__(256) void k_gram(const unsigned short* __restrict__ fH,
                                              const unsigned short* __restrict__ fL,
                                              const unsigned short* __restrict__ bH,
                                              const unsigned short* __restrict__ bL,
                                              float* __restrict__ GT,
                                              const float* __restrict__ ssq, const float* __restrict__ mask,
                                              float* __restrict__ norms, float* __restrict__ mmb) {
    if (blockIdx.z == 2) {                    // ---- nm segment (12 active blocks) ----
        int blk = blockIdx.y * 16 + blockIdx.x;
        if (blk >= 12) return;
        int idx = blk * 256 + threadIdx.x;    // 0..3071
        if (idx < 2048) {
            int q = idx & (Lq - 1);
            int bb = idx >> 10;
            int qy = q >> 5, qx = q & 31;
            float s = 0.1152f;
            for (int dk = -1; dk <= 1; ++dk) {
                int y = qy + dk; if ((unsigned)y >= (unsigned)HS) continue;
                for (int dl = -1; dl <= 1; ++dl) {
                    int x = qx + dl; if ((unsigned)x >= (unsigned)HS) continue;
                    s += ssq[bb * Lq + y * HS + x];
                }
            }
            norms[idx] = sqrtf(s);
        } else if (idx < 3072) {
            int q = idx - 2048;               // 0..1023
            int qy = q >> 5, qx = q & 31;
            float s = 0.f;
            for (int dk = -1; dk <= 1; ++dk) {
                int y = qy + dk; if ((unsigned)y >= (unsigned)HS) continue;
                for (int dl = -1; dl <= 1; ++dl) {
                    int x = qx + dl; if ((unsigned)x >= (unsigned)HS) continue;
                    s += mask[(8 * y) * 256 + 8 * x];
                }
            }
            mmb[q] = (s == 0.0f) ? 1.0f : 0.0f;
        }
        return;
    }
    const long bz = blockIdx.z;
    const unsigned short* AH = fH + bz * 131072;
    const unsigned short* AL = fL + bz * 131072;
    const unsigned short* BH = bH + bz * 131072;
    const unsigned short* BL = bL + bz * 131072;
    float* C = GT + (bz << 20);
    int t = threadIdx.x, w = t >> 6, lane = t & 63, quad = lane >> 4, l16 = lane & 15;
    int wm = blockIdx.x * 64 + (w & 1) * 32;
    int wn = blockIdx.y * 64 + (w >> 1) * 32;
    int ko = quad * 8;
    f32x4 acc[2][2] = {};
#pragma unroll
    for (int k0 = 0; k0 < 128; k0 += 32) {
        bf16x8 ah0 = *(const bf16x8*)&AH[(wm + l16) * 128 + ko + k0];
        bf16x8 ah1 = *(const bf16x8*)&AH[(wm + 16 + l16) * 128 + ko + k0];
        bf16x8 al0 = *(const bf16x8*)&AL[(wm + l16) * 128 + ko + k0];
        bf16x8 al1 = *(const bf16x8*)&AL[(wm + 16 + l16) * 128 + ko + k0];
        bf16x8 bh0 = *(const bf16x8*)&BH[(wn + l16) * 128 + ko + k0];
        bf16x8 bh1 = *(const bf16x8*)&BH[(wn + 16 + l16) * 128 + ko + k0];
        bf16x8 bl0 = *(const bf16x8*)&BL[(wn + l16) * 128 + ko + k0];
        bf16x8 bl1 = *(const bf16x8*)&BL[(wn + 16 + l16) * 128 + ko + k0];
        acc[0][0] = __builtin_amdgcn_mfma_f32_16x16x32_bf16(ah0, bh0, acc[0][0], 0, 0, 0);
        acc[0][1] = __builtin_amdgcn_mfma_f32_16x16x32_bf16(ah0, bh1, acc[0][1], 0, 0, 0);
        acc[1][0] = __builtin_amdgcn_mfma_f32_16x16x32_bf16(ah1, bh0, acc[1][0], 0, 0, 0);
        acc[1][1] = __builtin_amdgcn_mfma_f32_16x16x32_bf16(ah1, bh1, acc[1][1], 0, 0, 0);
        acc[0][0] = __builtin_amdgcn_mfma_f32_16x16x32_bf16(ah0, bl0, acc[0][0], 0, 0, 0);
        acc[0][1] = __builtin_amdgcn_mfma_f32_16x16x32_bf16(ah0, bl1, acc[0][1], 0, 0, 0);
        acc[1][0] = __builtin_amdgcn_mfma_f32_16x16x32_bf16(ah1, bl0, acc[1][0], 0, 0, 0);
        acc[1][1] = __builtin_amdgcn_mfma_f32_16x16x32_bf16(ah1, bl1, acc[1][1], 0, 0, 0);
        acc[0][0] = __builtin_amdgcn_mfma_f32_16x16x32_bf16(al0, bh0, acc[0][0], 0, 0, 0);
        acc[0][1] = __builtin_amdgcn_mfma_f32_16x16x32_bf16(al0, bh1, acc[0][1], 0, 0, 0);
        acc[1][0] = __builtin_amdgcn_mfma_f32_16x16x32_bf16(al1, bh0, acc[1][0], 0, 0, 0);
        acc[1][1] = __builtin_amdgcn_mfma_f32_16x16x32_bf16(al1, bh1, acc[1][1], 0, 0, 0);
    }
#pragma unroll
    for (int i = 0; i < 2; ++i)
#pragma unroll
        for (int j = 0; j < 2; ++j) {
            int mrow = wm + i * 16 + quad * 4;
            int ncol = wn + j * 16 + l16;
#pragma unroll
            for (int r = 0; r < 4; ++r)
                C[(long)(mrow + r) * Lq + ncol] = acc[i][j][r];
        }
}

// ---------------- S0T[p][q] = band9(GT) / norms[q]  (T-layout, r14-verified) ----------------
__global__ __launch_bounds__(256) void k_s0T(const float* __restrict__ GT, const float* __restrict__ norms,
                                             float* __restrict__ S0T) {
    int idx = blockIdx.x * 256 + threadIdx.x;  // 2*1024*1024
    int q  = idx & (Lq - 1);
    int pp = (idx >> 10) & (Lq - 1);
    int bb = idx >> 20;
    int qy = q >> 5, qx = q & 31, py = pp >> 5, px = pp & 31;
    const float* Gb = GT + ((long)bb << 20);
    float s = 0.f;
#pragma unroll
    for (int dk = -1; dk <= 1; ++dk) {
        if ((unsigned)(qy + dk) >= (unsigned)HS || (unsigned)(py + dk) >= (unsigned)HS) continue;
#pragma unroll
        for (int dl = -1; dl <= 1; ++dl) {
            if ((unsigned)(qx + dl) >= (unsigned)HS || (unsigned)(px + dl) >= (unsigned)HS) continue;
            int sft = dk * HS + dl;
            s += Gb[(long)(pp + sft) * Lq + (q + sft)];
        }
    }
    S0T[idx] = s / norms[bb * Lq + q];
}

// ---------------- FUSED fuse1+fuse2+softmax: one block = one softmax row ----------------
// block b: bb=b>>10, qrow=b&1023. 256 threads x 4 vals (p = j*256+t) = full 1024-col row.
// fuse12 per-output arithmetic order identical to r27 (q=qrow, p=pj). Softmax denominator
// reduced via butterfly+LDS (order differs from split kernel by ~1e-7 rel — tolerated).
// Writes attnT bf16 directly; S2T round-trip (8MB wr + 8MB rd) eliminated.
__global__ __launch_bounds__(256) void k_fuse12sm(const float* __restrict__ S0,
                                                  const float* __restrict__ mmb,
                                                  unsigned short* __restrict__ At) {
    int b = blockIdx.x;                       // 0..2047
    int bb = b >> 10, qrow = b & (Lq - 1);
    int t = threadIdx.x;
    const float* S = S0 + (long)bb * Lq * Lq;
    int hb = qrow >> 5, wb = qrow & 31;
    int ip = wb * HS + hb;
    float sv[4];
#pragma unroll
    for (int j = 0; j < 4; ++j) {
        int p = j * 256 + t;
        int hf = p >> 5, wf = p & 31;
        int jp = wf * HS + hf;
        float s = 0.f;
#pragma unroll
        for (int d = -1; d <= 1; ++d) {
            int tt = ip + d, r = jp + d;
            if ((unsigned)tt < (unsigned)Lq && (unsigned)r < (unsigned)Lq) {
                int q2 = (tt & 31) * HS + (tt >> 5);
                int p2 = (r & 31) * HS + (r >> 5);
                long base = (long)q2 * Lq + p2;
                float v = S[base];
                if (q2 > 0 && p2 > 0)             v += S[base - (Lq + 1)];
                if (q2 < Lq - 1 && p2 < Lq - 1)   v += S[base + (Lq + 1)];
                s += v;
            }
        }
        sv[j] = s;
    }
    // row softmax across 1024 values (4 waves)
    __shared__ float red[8];
    int lane = t & 63, w = t >> 6;
    float x[4]; float mx = -1e30f;
#pragma unroll
    for (int j = 0; j < 4; ++j) {
        int p = j * 256 + t;
        x[j] = sv[j] * mmb[p] * 10.0f;
        mx = fmaxf(mx, x[j]);
    }
    for (int off = 32; off > 0; off >>= 1) mx = fmaxf(mx, __shfl_xor(mx, off, 64));
    if (lane == 0) red[w] = mx;
    __syncthreads();
    mx = fmaxf(fmaxf(red[0], red[1]), fmaxf(red[2], red[3]));
    float e[4]; float sum = 0.f;
#pragma unroll
    for (int j = 0; j < 4; ++j) { e[j] = __expf(x[j] - mx); sum += e[j]; }
    for (int off = 32; off > 0; off >>= 1) sum += __shfl_xor(sum, off, 64);
    if (lane == 0) red[4 + w] = sum;          // disjoint slots — no race with red[0..3] reads
    __syncthreads();
    sum = (red[4] + red[5]) + (red[6] + red[7]);
    float inv = 1.0f / sum;
    unsigned short* orow = At + ((long)bb << 20) + (long)qrow * Lq;
#pragma unroll
    for (int j = 0; j < 4; ++j) {
        int p = j * 256 + t;
        orow[p] = f2bf(e[j] * mmb[p] * inv);
    }
}

// ---------------- MFMA GEMM: 128x64 tile, STATIC dbuf, counted vmcnt(6), XOR swizzle ----------------
// P[m][p] = sum_q Wm[m][q]*attnT[p][q]. BM=128, BN=64, BK=64, grid (16,16,2) = 2 blocks/CU.
__global__ __launch_bounds__(256) void k_gemm_mfma(const unsigned short* __restrict__ WmA,
                                                   const unsigned short* __restrict__ At,
                                                   float* __restrict__ Cm) {
    const long bz = blockIdx.z;
    const unsigned short* A = WmA + bz * (2048L * Lq);
    const unsigned short* B = At  + bz * ((long)Lq * Lq);
    float* C = Cm + bz * (2048L * Lq);
    __shared__ __align__(16) unsigned short As0[128 * 64], As1[128 * 64];  // 16 KB each
    __shared__ __align__(16) unsigned short Bs0[64 * 64],  Bs1[64 * 64];   //  8 KB each
    int t = threadIdx.x;
    int w = t >> 6, lane = t & 63, quad = lane >> 4, l16 = lane & 15;
    int wr = w >> 1, wc = w & 1;             // wave tile: rows wr*64.., cols wc*32..
    int m0 = blockIdx.x * 128, n0 = blockIdx.y * 64;
    int srow  = t >> 3;                       // 0..31: row within a 32-row staging round
    int scolS = ((t & 7) ^ ((t >> 3) & 7)) << 3;  // pre-swizzled global source col (elems)
    int sdst  = t * 8;                        // linear LDS dest (elems) = t*16 bytes
    int xr    = l16 & 7;                      // read-side row XOR key
    f32x4 acc[4][2] = {};

#define STG(AS, BS, kk) do {                                                        \
    _Pragma("unroll")                                                               \
    for (int r = 0; r < 4; ++r)  /* A: 128 rows = 4 rounds */                       \
        gload16(A + (long)(m0 + r * 32 + srow) * Lq + (kk) + scolS,                 \
                &AS[r * 2048 + sdst]);                                              \
    _Pragma("unroll")                                                               \
    for (int r = 0; r < 2; ++r)  /* B: 64 rows = 2 rounds */                        \
        gload16(B + (long)(n0 + r * 32 + srow) * Lq + (kk) + scolS,                 \
                &BS[r * 2048 + sdst]);                                              \
} while (0)

#define CMP(AS, BS) do {                                                            \
    _Pragma("unroll")                                                               \
    for (int ks = 0; ks < 2; ++ks) {                                                \
        int slot = ((ks * 4 + quad) ^ xr) << 3;                                     \
        bf16x8 a[4], b[2];                                                          \
        _Pragma("unroll")                                                           \
        for (int i = 0; i < 4; ++i)                                                 \
            a[i] = *(const bf16x8*)&AS[(wr * 64 + i * 16 + l16) * 64 + slot];       \
        _Pragma("unroll")                                                           \
        for (int j = 0; j < 2; ++j)                                                 \
            b[j] = *(const bf16x8*)&BS[(wc * 32 + j * 16 + l16) * 64 + slot];       \
        _Pragma("unroll")                                                           \
        for (int i = 0; i < 4; ++i)                                                 \
            _Pragma("unroll")                                                       \
            for (int j = 0; j < 2; ++j)                                             \
                acc[i][j] = __builtin_amdgcn_mfma_f32_16x16x32_bf16(a[i], b[j], acc[i][j], 0, 0, 0); \
    }                                                                               \
} while (0)

#define SBAR() do { __builtin_amdgcn_s_barrier(); asm volatile("" ::: "memory"); } while (0)
#define WAITV6() do { asm volatile("s_waitcnt vmcnt(6)" ::: "memory"); __builtin_amdgcn_sched_barrier(0); } while (0)
#define WAITV0() do { asm volatile("s_waitcnt vmcnt(0)" ::: "memory"); __builtin_amdgcn_sched_barrier(0); } while (0)

    STG(As0, Bs0, 0);                         // tile 0: 6 loads in flight
    STG(As1, Bs1, 64);                        // tile 1: 12 in flight
    for (int k0 = 0; k0 < Lq; k0 += 128) {
        WAITV6();                             // oldest 6 (As0/Bs0 tile) landed
        SBAR();
        CMP(As0, Bs0);
        SBAR();
        if (k0 + 128 < Lq) STG(As0, Bs0, k0 + 128);   // back to 12 in flight
        if (k0 + 128 < Lq) WAITV6(); else WAITV0();   // As1/Bs1 tile landed
        SBAR();
        CMP(As1, Bs1);
        SBAR();
        if (k0 + 192 < Lq) STG(As1, Bs1, k0 + 192);
    }
#undef STG
#undef CMP
#undef SBAR
#undef WAITV6
#undef WAITV0
#pragma unroll
    for (int i = 0; i < 4; ++i) {
        int mrow = m0 + wr * 64 + i * 16 + quad * 4;
#pragma unroll
        for (int j = 0; j < 2; ++j) {
            int ncol = n0 + wc * 32 + j * 16 + l16;
#pragma unroll
            for (int r = 0; r < 4; ++r)
                C[(long)(mrow + r) * Lq + ncol] = acc[i][j][r];
        }
    }
}

// ---------------- literal conv epilogue: fp32 tap-sum, /4, store fp32 (r11-verified) ----------------
__global__ __launch_bounds__(256) void k_epi2(const float* __restrict__ P, float* __restrict__ out) {
    int idx = blockIdx.x * 256 + threadIdx.x;   // 1048576
    int ox = idx & 63, oy = (idx >> 6) & 63, c = (idx >> 12) & 127, bb = idx >> 19;
    const float* Pb = P + (long)bb * 2048 * Lq;
    float s = 0.f;
#pragma unroll
    for (int u = 0; u < 4; ++u) {
        int t = oy + u - 2;
        if (t & 1) continue;
        int iy = t >> 1;
        if ((unsigned)iy >= (unsigned)HS) continue;
#pragma unroll
        for (int v = 0; v < 4; ++v) {
            int r = ox + v - 2;
            if (r & 1) continue;
            int ix = r >> 1;
            if ((unsigned)ix >= (unsigned)HS) continue;
            s += Pb[(long)((c << 4) + (3 - u) * 4 + (3 - v)) * Lq + (iy << 5) + ix];
        }
    }
    out[idx] = 0.25f * s;
}

extern "C" void kernel_launch(void* const* d_in, const int* in_sizes, int n_in,
                              void* d_out, int out_size, void* d_ws, size_t ws_size,
                              hipStream_t stream) {
    const float* f    = (const float*)d_in[0];
    const float* bsrc = (const float*)d_in[1];
    const float* mask = (const float*)d_in[2];
    float* out = (float*)d_out;
    float* ws = (float*)d_ws;

    // workspace (floats): ~8.9M = 35.7 MB (S2T slot now unused)
    float* ssq   = ws;                        // 2048
    float* norms = ssq   + 2048;              // 2048
    float* mmb   = norms + 2048;              // 1024
    unsigned short* fH = (unsigned short*)(mmb + 1024);      // 262144 ushorts each
    unsigned short* fL = fH + 262144;
    unsigned short* bH = fL + 262144;
    unsigned short* bL = bH + 262144;
    float* GTa   = (float*)(bL + 262144);     // 2097152 : GT -> attnT(bf16)
    float* C1    = GTa + 2097152;             // 2097152 : S0T -> P[0:2M]
    float* C2    = C1  + 2097152;             // 2097152 : P[2M:4M]
    unsigned short* Wm = (unsigned short*)(C2 + 2097152);    // 4194304 ushorts
    float* S0T  = C1;
    unsigned short* attnT = (unsigned short*)GTa;  // GT dead after k_s0T
    float* P    = C1;      // spans C1+C2; S0T dead after fuse12sm

    hipLaunchKernelGGL(k_prep3,     dim3(16896),      dim3(256), 0, stream, f, bsrc, fH, fL, bH, bL, ssq, Wm);
    hipLaunchKernelGGL(k_gram,      dim3(16, 16, 3),  dim3(256), 0, stream, fH, fL, bH, bL, GTa, ssq, mask, norms, mmb);
    hipLaunchKernelGGL(k_s0T,       dim3(8192),       dim3(256), 0, stream, GTa, norms, S0T);
    hipLaunchKernelGGL(k_fuse12sm,  dim3(2048),       dim3(256), 0, stream, S0T, mmb, attnT);
    hipLaunchKernelGGL(k_gemm_mfma, dim3(16, 16, 2),  dim3(256), 0, stream, Wm, attnT, P);
    hipLaunchKernelGGL(k_epi2,      dim3(4096),       dim3(256), 0, stream, P, out);
}

// Round 13
// 131.196 us; speedup vs baseline: 1.1534x; 1.0041x over previous
//
#include <hip/hip_runtime.h>
#include <hip/hip_bf16.h>
#include <math.h>

constexpr int HS = 32;      // half spatial (32x32 grids)
constexpr int Lq = 1024;    // HS*HS
constexpr int CN = 128;     // channels
// batches = 2. Inputs fp32 (f, b, mask). Output fp32 (r11-verified).
// R31: T1 XCD-aware swizzle on gemm grid (1D 512 blocks, 512%8==0 -> simple bijective
// remap l -> (l%8)*64 + l/8). Each XCD owns 64 consecutive tiles = 4 n-groups of one
// batch -> A panel set (4MB) L2-resident per XCD; L3 re-fetch cut ~3-4x. Mechanism:
// r28 ablation gemm=14us = 192MB tile fetch @13.7TB/s -> fetch-BW bound (explains
// R26-R29 scheduling nulls). Pure index remap -> bit-identical output.
// All else byte-identical to r30 (131.7 best).

typedef short bf16x8 __attribute__((ext_vector_type(8)));
typedef float f32x4  __attribute__((ext_vector_type(4)));

__device__ inline unsigned short f2bf(float x) {   // RNE float->bf16 bits
    union { float f; unsigned int u; } c; c.f = x;
    return (unsigned short)((c.u + 0x7FFF + ((c.u >> 16) & 1)) >> 16);
}
__device__ inline float bf2f(unsigned short h) {
    union { unsigned int u; float f; } c; c.u = ((unsigned int)h) << 16;
    return c.f;
}

// async global->LDS, 16B per lane (wave-uniform LDS base + lane*16 layout)
__device__ inline void gload16(const void* g, void* l) {
    __builtin_amdgcn_global_load_lds(
        (const __attribute__((address_space(1))) unsigned int*)g,
        (__attribute__((address_space(3))) unsigned int*)l, 16, 0, 0);
}

// ---------------- merged prep+ssq+wm: one launch, two grid segments ----------------
__global__ __launch_bounds__(256) void k_prep3(const float* __restrict__ f,
                                               const float* __restrict__ bsrc,
                                               unsigned short* __restrict__ fH, unsigned short* __restrict__ fL,
                                               unsigned short* __restrict__ bH, unsigned short* __restrict__ bL,
                                               float* __restrict__ ssq,
                                               unsigned short* __restrict__ Wm) {
    int tx = threadIdx.x;
    if (blockIdx.x < 512) {
        int u = blockIdx.x * 4 + (tx >> 6);  // 0..2047 = bb*1024 + p
        int lane = tx & 63;
        int p = u & (Lq - 1), bb = u >> 10;
        int py = p >> 5, px = p & 31;
        long srcbase = (((long)bb * CN) * 64 + 2 * py) * 64 + 2 * px;
        float s = 0.f;
#pragma unroll
        for (int i = 0; i < 2; ++i) {
            int c = lane + i * 64;
            long src = srcbase + (long)c * 4096;
            float fv = f[src], bv = bsrc[src];
            int o = u * CN + c;
            unsigned short fh = f2bf(fv), bh = f2bf(bv);
            fH[o] = fh; fL[o] = f2bf(fv - bf2f(fh));
            bH[o] = bh; bL[o] = f2bf(bv - bf2f(bh));
            s += bv * bv;
        }
        for (int off = 32; off > 0; off >>= 1) s += __shfl_down(s, off, 64);
        if (lane == 0) ssq[u] = s;
    } else {
        int idx = (blockIdx.x - 512) * 256 + tx;   // 2*2048*1024
        int q  = idx & (Lq - 1);
        int m  = (idx >> 10) & 2047;
        int bb = idx >> 21;
        int c = m >> 4, u = (m >> 2) & 3, v = m & 3;
        int qy = q >> 5, qx = q & 31;
        int y = 2 * qy + u - 1, x = 2 * qx + v - 1;
        float val = 0.f;
        if ((unsigned)y < 64u && (unsigned)x < 64u)
            val = bsrc[(((long)bb * CN + c) * 64 + y) * 64 + x];
        Wm[idx] = f2bf(val);
    }
}

// ---------------- Gram MFMA bf16x2 + merged nm segment (blockIdx.z==2) ----------------
__global__ __launch_bounds__(256) void k_gram(const unsigned short* __restrict__ fH,
                                              const unsigned short* __restrict__ fL,
                                              const unsigned short* __restrict__ bH,
                                              const unsigned short* __restrict__ bL,
                                              float* __restrict__ GT,
                                              const float* __restrict__ ssq, const float* __restrict__ mask,
                                              float* __restrict__ norms, float* __restrict__ mmb) {
    if (blockIdx.z == 2) {                    // ---- nm segment (12 active blocks) ----
        int blk = blockIdx.y * 16 + blockIdx.x;
        if (blk >= 12) return;
        int idx = blk * 256 + threadIdx.x;    // 0..3071
        if (idx < 2048) {
            int q = idx & (Lq - 1);
            int bb = idx >> 10;
            int qy = q >> 5, qx = q & 31;
            float s = 0.1152f;
            for (int dk = -1; dk <= 1; ++dk) {
                int y = qy + dk; if ((unsigned)y >= (unsigned)HS) continue;
                for (int dl = -1; dl <= 1; ++dl) {
                    int x = qx + dl; if ((unsigned)x >= (unsigned)HS) continue;
                    s += ssq[bb * Lq + y * HS + x];
                }
            }
            norms[idx] = sqrtf(s);
        } else if (idx < 3072) {
            int q = idx - 2048;               // 0..1023
            int qy = q >> 5, qx = q & 31;
            float s = 0.f;
            for (int dk = -1; dk <= 1; ++dk) {
                int y = qy + dk; if ((unsigned)y >= (unsigned)HS) continue;
                for (int dl = -1; dl <= 1; ++dl) {
                    int x = qx + dl; if ((unsigned)x >= (unsigned)HS) continue;
                    s += mask[(8 * y) * 256 + 8 * x];
                }
            }
            mmb[q] = (s == 0.0f) ? 1.0f : 0.0f;
        }
        return;
    }
    const long bz = blockIdx.z;
    const unsigned short* AH = fH + bz * 131072;
    const unsigned short* AL = fL + bz * 131072;
    const unsigned short* BH = bH + bz * 131072;
    const unsigned short* BL = bL + bz * 131072;
    float* C = GT + (bz << 20);
    int t = threadIdx.x, w = t >> 6, lane = t & 63, quad = lane >> 4, l16 = lane & 15;
    int wm = blockIdx.x * 64 + (w & 1) * 32;
    int wn = blockIdx.y * 64 + (w >> 1) * 32;
    int ko = quad * 8;
    f32x4 acc[2][2] = {};
#pragma unroll
    for (int k0 = 0; k0 < 128; k0 += 32) {
        bf16x8 ah0 = *(const bf16x8*)&AH[(wm + l16) * 128 + ko + k0];
        bf16x8 ah1 = *(const bf16x8*)&AH[(wm + 16 + l16) * 128 + ko + k0];
        bf16x8 al0 = *(const bf16x8*)&AL[(wm + l16) * 128 + ko + k0];
        bf16x8 al1 = *(const bf16x8*)&AL[(wm + 16 + l16) * 128 + ko + k0];
        bf16x8 bh0 = *(const bf16x8*)&BH[(wn + l16) * 128 + ko + k0];
        bf16x8 bh1 = *(const bf16x8*)&BH[(wn + 16 + l16) * 128 + ko + k0];
        bf16x8 bl0 = *(const bf16x8*)&BL[(wn + l16) * 128 + ko + k0];
        bf16x8 bl1 = *(const bf16x8*)&BL[(wn + 16 + l16) * 128 + ko + k0];
        acc[0][0] = __builtin_amdgcn_mfma_f32_16x16x32_bf16(ah0, bh0, acc[0][0], 0, 0, 0);
        acc[0][1] = __builtin_amdgcn_mfma_f32_16x16x32_bf16(ah0, bh1, acc[0][1], 0, 0, 0);
        acc[1][0] = __builtin_amdgcn_mfma_f32_16x16x32_bf16(ah1, bh0, acc[1][0], 0, 0, 0);
        acc[1][1] = __builtin_amdgcn_mfma_f32_16x16x32_bf16(ah1, bh1, acc[1][1], 0, 0, 0);
        acc[0][0] = __builtin_amdgcn_mfma_f32_16x16x32_bf16(ah0, bl0, acc[0][0], 0, 0, 0);
        acc[0][1] = __builtin_amdgcn_mfma_f32_16x16x32_bf16(ah0, bl1, acc[0][1], 0, 0, 0);
        acc[1][0] = __builtin_amdgcn_mfma_f32_16x16x32_bf16(ah1, bl0, acc[1][0], 0, 0, 0);
        acc[1][1] = __builtin_amdgcn_mfma_f32_16x16x32_bf16(ah1, bl1, acc[1][1], 0, 0, 0);
        acc[0][0] = __builtin_amdgcn_mfma_f32_16x16x32_bf16(al0, bh0, acc[0][0], 0, 0, 0);
        acc[0][1] = __builtin_amdgcn_mfma_f32_16x16x32_bf16(al0, bh1, acc[0][1], 0, 0, 0);
        acc[1][0] = __builtin_amdgcn_mfma_f32_16x16x32_bf16(al1, bh0, acc[1][0], 0, 0, 0);
        acc[1][1] = __builtin_amdgcn_mfma_f32_16x16x32_bf16(al1, bh1, acc[1][1], 0, 0, 0);
    }
#pragma unroll
    for (int i = 0; i < 2; ++i)
#pragma unroll
        for (int j = 0; j < 2; ++j) {
            int mrow = wm + i * 16 + quad * 4;
            int ncol = wn + j * 16 + l16;
#pragma unroll
            for (int r = 0; r < 4; ++r)
                C[(long)(mrow + r) * Lq + ncol] = acc[i][j][r];
        }
}

// ---------------- S0T[p][q] = band9(GT) / norms[q]  (T-layout, r14-verified) ----------------
__global__ __launch_bounds__(256) void k_s0T(const float* __restrict__ GT, const float* __restrict__ norms,
                                             float* __restrict__ S0T) {
    int idx = blockIdx.x * 256 + threadIdx.x;  // 2*1024*1024
    int q  = idx & (Lq - 1);
    int pp = (idx >> 10) & (Lq - 1);
    int bb = idx >> 20;
    int qy = q >> 5, qx = q & 31, py = pp >> 5, px = pp & 31;
    const float* Gb = GT + ((long)bb << 20);
    float s = 0.f;
#pragma unroll
    for (int dk = -1; dk <= 1; ++dk) {
        if ((unsigned)(qy + dk) >= (unsigned)HS || (unsigned)(py + dk) >= (unsigned)HS) continue;
#pragma unroll
        for (int dl = -1; dl <= 1; ++dl) {
            if ((unsigned)(qx + dl) >= (unsigned)HS || (unsigned)(px + dl) >= (unsigned)HS) continue;
            int sft = dk * HS + dl;
            s += Gb[(long)(pp + sft) * Lq + (q + sft)];
        }
    }
    S0T[idx] = s / norms[bb * Lq + q];
}

// ---------------- FUSED fuse1+fuse2+softmax: one block = one softmax row (r30-verified) ----------------
__global__ __launch_bounds__(256) void k_fuse12sm(const float* __restrict__ S0,
                                                  const float* __restrict__ mmb,
                                                  unsigned short* __restrict__ At) {
    int b = blockIdx.x;                       // 0..2047
    int bb = b >> 10, qrow = b & (Lq - 1);
    int t = threadIdx.x;
    const float* S = S0 + (long)bb * Lq * Lq;
    int hb = qrow >> 5, wb = qrow & 31;
    int ip = wb * HS + hb;
    float sv[4];
#pragma unroll
    for (int j = 0; j < 4; ++j) {
        int p = j * 256 + t;
        int hf = p >> 5, wf = p & 31;
        int jp = wf * HS + hf;
        float s = 0.f;
#pragma unroll
        for (int d = -1; d <= 1; ++d) {
            int tt = ip + d, r = jp + d;
            if ((unsigned)tt < (unsigned)Lq && (unsigned)r < (unsigned)Lq) {
                int q2 = (tt & 31) * HS + (tt >> 5);
                int p2 = (r & 31) * HS + (r >> 5);
                long base = (long)q2 * Lq + p2;
                float v = S[base];
                if (q2 > 0 && p2 > 0)             v += S[base - (Lq + 1)];
                if (q2 < Lq - 1 && p2 < Lq - 1)   v += S[base + (Lq + 1)];
                s += v;
            }
        }
        sv[j] = s;
    }
    // row softmax across 1024 values (4 waves)
    __shared__ float red[8];
    int lane = t & 63, w = t >> 6;
    float x[4]; float mx = -1e30f;
#pragma unroll
    for (int j = 0; j < 4; ++j) {
        int p = j * 256 + t;
        x[j] = sv[j] * mmb[p] * 10.0f;
        mx = fmaxf(mx, x[j]);
    }
    for (int off = 32; off > 0; off >>= 1) mx = fmaxf(mx, __shfl_xor(mx, off, 64));
    if (lane == 0) red[w] = mx;
    __syncthreads();
    mx = fmaxf(fmaxf(red[0], red[1]), fmaxf(red[2], red[3]));
    float e[4]; float sum = 0.f;
#pragma unroll
    for (int j = 0; j < 4; ++j) { e[j] = __expf(x[j] - mx); sum += e[j]; }
    for (int off = 32; off > 0; off >>= 1) sum += __shfl_xor(sum, off, 64);
    if (lane == 0) red[4 + w] = sum;          // disjoint slots — no race with red[0..3] reads
    __syncthreads();
    sum = (red[4] + red[5]) + (red[6] + red[7]);
    float inv = 1.0f / sum;
    unsigned short* orow = At + ((long)bb << 20) + (long)qrow * Lq;
#pragma unroll
    for (int j = 0; j < 4; ++j) {
        int p = j * 256 + t;
        orow[p] = f2bf(e[j] * mmb[p] * inv);
    }
}

// ---------------- MFMA GEMM: 128x64 tile, STATIC dbuf, counted vmcnt(6), XOR swizzle ----------------
// P[m][p] = sum_q Wm[m][q]*attnT[p][q]. BM=128, BN=64, BK=64. Grid = 1D 512 blocks,
// R31: XCD-aware bijective remap l -> (l%8)*64 + l/8, then decode z/n/m (x-major m,
// so blocks within an n-group share the B-panel and an XCD's 64 tiles span 4 n-groups
// of one batch -> A set L2-resident per XCD).
__global__ __launch_bounds__(256) void k_gemm_mfma(const unsigned short* __restrict__ WmA,
                                                   const unsigned short* __restrict__ At,
                                                   float* __restrict__ Cm) {
    int l = blockIdx.x;                       // 0..511
    int swz = (l & 7) * 64 + (l >> 3);        // bijective (512 % 8 == 0)
    int bm = swz & 15;                        // m-tile (fastest -> shares B within group)
    int bn = (swz >> 4) & 15;                 // n-tile
    const long bz = swz >> 8;                 // batch
    const unsigned short* A = WmA + bz * (2048L * Lq);
    const unsigned short* B = At  + bz * ((long)Lq * Lq);
    float* C = Cm + bz * (2048L * Lq);
    __shared__ __align__(16) unsigned short As0[128 * 64], As1[128 * 64];  // 16 KB each
    __shared__ __align__(16) unsigned short Bs0[64 * 64],  Bs1[64 * 64];   //  8 KB each
    int t = threadIdx.x;
    int w = t >> 6, lane = t & 63, quad = lane >> 4, l16 = lane & 15;
    int wr = w >> 1, wc = w & 1;             // wave tile: rows wr*64.., cols wc*32..
    int m0 = bm * 128, n0 = bn * 64;
    int srow  = t >> 3;                       // 0..31: row within a 32-row staging round
    int scolS = ((t & 7) ^ ((t >> 3) & 7)) << 3;  // pre-swizzled global source col (elems)
    int sdst  = t * 8;                        // linear LDS dest (elems) = t*16 bytes
    int xr    = l16 & 7;                      // read-side row XOR key
    f32x4 acc[4][2] = {};

#define STG(AS, BS, kk) do {                                                        \
    _Pragma("unroll")                                                               \
    for (int r = 0; r < 4; ++r)  /* A: 128 rows = 4 rounds */                       \
        gload16(A + (long)(m0 + r * 32 + srow) * Lq + (kk) + scolS,                 \
                &AS[r * 2048 + sdst]);                                              \
    _Pragma("unroll")                                                               \
    for (int r = 0; r < 2; ++r)  /* B: 64 rows = 2 rounds */                        \
        gload16(B + (long)(n0 + r * 32 + srow) * Lq + (kk) + scolS,                 \
                &BS[r * 2048 + sdst]);                                              \
} while (0)

#define CMP(AS, BS) do {                                                            \
    _Pragma("unroll")                                                               \
    for (int ks = 0; ks < 2; ++ks) {                                                \
        int slot = ((ks * 4 + quad) ^ xr) << 3;                                     \
        bf16x8 a[4], b[2];                                                          \
        _Pragma("unroll")                                                           \
        for (int i = 0; i < 4; ++i)                                                 \
            a[i] = *(const bf16x8*)&AS[(wr * 64 + i * 16 + l16) * 64 + slot];       \
        _Pragma("unroll")                                                           \
        for (int j = 0; j < 2; ++j)                                                 \
            b[j] = *(const bf16x8*)&BS[(wc * 32 + j * 16 + l16) * 64 + slot];       \
        _Pragma("unroll")                                                           \
        for (int i = 0; i < 4; ++i)                                                 \
            _Pragma("unroll")                                                       \
            for (int j = 0; j < 2; ++j)                                             \
                acc[i][j] = __builtin_amdgcn_mfma_f32_16x16x32_bf16(a[i], b[j], acc[i][j], 0, 0, 0); \
    }                                                                               \
} while (0)

#define SBAR() do { __builtin_amdgcn_s_barrier(); asm volatile("" ::: "memory"); } while (0)
#define WAITV6() do { asm volatile("s_waitcnt vmcnt(6)" ::: "memory"); __builtin_amdgcn_sched_barrier(0); } while (0)
#define WAITV0() do { asm volatile("s_waitcnt vmcnt(0)" ::: "memory"); __builtin_amdgcn_sched_barrier(0); } while (0)

    STG(As0, Bs0, 0);                         // tile 0: 6 loads in flight
    STG(As1, Bs1, 64);                        // tile 1: 12 in flight
    for (int k0 = 0; k0 < Lq; k0 += 128) {
        WAITV6();                             // oldest 6 (As0/Bs0 tile) landed
        SBAR();
        CMP(As0, Bs0);
        SBAR();
        if (k0 + 128 < Lq) STG(As0, Bs0, k0 + 128);   // back to 12 in flight
        if (k0 + 128 < Lq) WAITV6(); else WAITV0();   // As1/Bs1 tile landed
        SBAR();
        CMP(As1, Bs1);
        SBAR();
        if (k0 + 192 < Lq) STG(As1, Bs1, k0 + 192);
    }
#undef STG
#undef CMP
#undef SBAR
#undef WAITV6
#undef WAITV0
#pragma unroll
    for (int i = 0; i < 4; ++i) {
        int mrow = m0 + wr * 64 + i * 16 + quad * 4;
#pragma unroll
        for (int j = 0; j < 2; ++j) {
            int ncol = n0 + wc * 32 + j * 16 + l16;
#pragma unroll
            for (int r = 0; r < 4; ++r)
                C[(long)(mrow + r) * Lq + ncol] = acc[i][j][r];
        }
    }
}

// ---------------- literal conv epilogue: fp32 tap-sum, /4, store fp32 (r11-verified) ----------------
__global__ __launch_bounds__(256) void k_epi2(const float* __restrict__ P, float* __restrict__ out) {
    int idx = blockIdx.x * 256 + threadIdx.x;   // 1048576
    int ox = idx & 63, oy = (idx >> 6) & 63, c = (idx >> 12) & 127, bb = idx >> 19;
    const float* Pb = P + (long)bb * 2048 * Lq;
    float s = 0.f;
#pragma unroll
    for (int u = 0; u < 4; ++u) {
        int t = oy + u - 2;
        if (t & 1) continue;
        int iy = t >> 1;
        if ((unsigned)iy >= (unsigned)HS) continue;
#pragma unroll
        for (int v = 0; v < 4; ++v) {
            int r = ox + v - 2;
            if (r & 1) continue;
            int ix = r >> 1;
            if ((unsigned)ix >= (unsigned)HS) continue;
            s += Pb[(long)((c << 4) + (3 - u) * 4 + (3 - v)) * Lq + (iy << 5) + ix];
        }
    }
    out[idx] = 0.25f * s;
}

extern "C" void kernel_launch(void* const* d_in, const int* in_sizes, int n_in,
                              void* d_out, int out_size, void* d_ws, size_t ws_size,
                              hipStream_t stream) {
    const float* f    = (const float*)d_in[0];
    const float* bsrc = (const float*)d_in[1];
    const float* mask = (const float*)d_in[2];
    float* out = (float*)d_out;
    float* ws = (float*)d_ws;

    // workspace (floats): ~8.9M = 35.7 MB (S2T slot now unused)
    float* ssq   = ws;                        // 2048
    float* norms = ssq   + 2048;              // 2048
    float* mmb   = norms + 2048;              // 1024
    unsigned short* fH = (unsigned short*)(mmb + 1024);      // 262144 ushorts each
    unsigned short* fL = fH + 262144;
    unsigned short* bH = fL + 262144;
    unsigned short* bL = bH + 262144;
    float* GTa   = (float*)(bL + 262144);     // 2097152 : GT -> attnT(bf16)
    float* C1    = GTa + 2097152;             // 2097152 : S0T -> P[0:2M]
    float* C2    = C1  + 2097152;             // 2097152 : P[2M:4M]
    unsigned short* Wm = (unsigned short*)(C2 + 2097152);    // 4194304 ushorts
    float* S0T  = C1;
    unsigned short* attnT = (unsigned short*)GTa;  // GT dead after k_s0T
    float* P    = C1;      // spans C1+C2; S0T dead after fuse12sm

    hipLaunchKernelGGL(k_prep3,     dim3(16896),      dim3(256), 0, stream, f, bsrc, fH, fL, bH, bL, ssq, Wm);
    hipLaunchKernelGGL(k_gram,      dim3(16, 16, 3),  dim3(256), 0, stream, fH, fL, bH, bL, GTa, ssq, mask, norms, mmb);
    hipLaunchKernelGGL(k_s0T,       dim3(8192),       dim3(256), 0, stream, GTa, norms, S0T);
    hipLaunchKernelGGL(k_fuse12sm,  dim3(2048),       dim3(256), 0, stream, S0T, mmb, attnT);
    hipLaunchKernelGGL(k_gemm_mfma, dim3(512),        dim3(256), 0, stream, Wm, attnT, P);
    hipLaunchKernelGGL(k_epi2,      dim3(4096),       dim3(256), 0, stream, P, out);
}